// Round 10
// baseline (210.420 us; speedup 1.0000x reference)
//
#include <hip/hip_runtime.h>
#include <hip/hip_bf16.h>

#define N_ATOMS 10000
#define N_PAIRS 100000
#define HH 64
#define MAXZ 100

typedef _Float16 h2_t __attribute__((ext_vector_type(2)));

constexpr float RBF_START = 0.6065306597126334f;
constexpr float RBF_STEP  = (1.0f - RBF_START) / 31.0f;
constexpr float RBF_BETA  = 1.0f / ((0.0625f * (1.0f - RBF_START)) * (0.0625f * (1.0f - RBF_START)));
constexpr float LOG2E     = 1.4426950408889634f;
constexpr float NEG_ALPHA_L2 = -10.0f * LOG2E;
constexpr float NEG_BETA_L2  = -RBF_BETA * LOG2E;

// ---- f32 param layout in WF (element offsets) ----
#define OFF_EMB   0
#define OFF_W2    6400
#define OFF_B2    14592
#define OFF_D1W   14656
#define OFF_D1B   16704
#define OFF_D2W   16768
#define OFF_D2B   18816
#define OFF_D3W   18880
#define OFF_D3B   20928
#define OFF_LT0   20992
#define OFF_LT1   25088
#define OFF_LT2   29184
#define OFF_L1W   33280
#define OFF_L1B   41472
#define OFF_L2W   41600
#define OFF_L2B   66176
#define OFF_LNG   66368
#define OFF_LNB   66432
#define N_PARAMF  66496

// packed-half (uint) region layout inside PH
#define PH_DP   0        // 3 x 64 x 16 uints
#define PH_L1   3072     // 128 x 32
#define PH_L2   7168     // 192 x 64
#define PH_LT   19456    // 3 x 64 x 32
#define PH_N    25600

// ws byte offsets
#define WS_WF     0
#define WS_CNT    266240
#define WS_OFF    307200
#define WS_CUR    348160
#define WS_T1     389120
#define WS_T2     414720
#define WS_PH     440320
#define WS_DPK    542720
#define WS_ZNL    2142720
#define WS_RBF    2542720
#define WS_ACCH   8942720

__device__ __forceinline__ float bf2f(unsigned short u) {
    return __uint_as_float(((unsigned int)u) << 16);
}
__device__ __forceinline__ float fexp2(float x) { return __builtin_amdgcn_exp2f(x); }
__device__ __forceinline__ float fcos2pi(float x) { return __builtin_amdgcn_cosf(x); }
__device__ __forceinline__ float fsilu(float x) { return x / (1.0f + fexp2(-LOG2E * x)); }
__device__ __forceinline__ h2_t u2h(unsigned u) { return __builtin_bit_cast(h2_t, u); }
__device__ __forceinline__ unsigned packh2(float a, float b) {
    h2_t v; v.x = (_Float16)a; v.y = (_Float16)b;
    return __builtin_bit_cast(unsigned, v);
}

#if __has_builtin(__builtin_amdgcn_fdot2)
__device__ __forceinline__ float FDOT2(h2_t a, h2_t b, float c) {
    return __builtin_amdgcn_fdot2(a, b, c, false);
}
#else
__device__ __forceinline__ float FDOT2(h2_t a, h2_t b, float c) {
    return c + (float)a.x * (float)b.x + (float)a.y * (float)b.y;
}
#endif
__device__ __forceinline__ float dot16v(uint4 a, uint4 b, float acc) {
    acc = FDOT2(u2h(a.x), u2h(b.x), acc);
    acc = FDOT2(u2h(a.y), u2h(b.y), acc);
    acc = FDOT2(u2h(a.z), u2h(b.z), acc);
    acc = FDOT2(u2h(a.w), u2h(b.w), acc);
    return acc;
}
__device__ __forceinline__ float dot16h(const uint4* w, const uint4* x, float acc) {
    return dot16v(*w, *x, acc);
}

// ---- buffer layout probe (round 3/4 forensics): 1 = u16/bf16 array, 0 = f32 ----
__device__ int classify64(const unsigned short* b, int lane) {
    unsigned short x = b[lane];
    int e = (x >> 7) & 0xFF;
    bool implaus = (x != 0) && (e < 96 || e > 133);
    bool zeroeven = ((lane & 1) == 0) && (x == 0);
    unsigned long long mi = __ballot(implaus);
    unsigned long long mz = __ballot(zeroeven);
    if (__popcll(mz) == 32) return 0;
    if (__popcll(mi) >= 8) return 0;
    return 1;
}

struct ConvArgs { const void* src[18]; float* dst; };

// conv (params -> f32 WF) + pair counting, fused. cnt pre-zeroed by memset.
__global__ void k_prep(ConvArgs a, const int* __restrict__ pidx, int* __restrict__ cnt) {
    const int sizes[18] = {6400,8192,64,2048,64,2048,64,2048,64,4096,4096,4096,8192,128,24576,192,64,64};
    __shared__ int fl;
    if (threadIdx.x < 64) {
        int f = classify64((const unsigned short*)a.src[0], threadIdx.x);
        if (threadIdx.x == 0) fl = f;
    }
    __syncthreads();
    int t = blockIdx.x * 256 + threadIdx.x;
    if (t < N_PARAMF) {
        int acc = 0, seg = 0, off = t;
        #pragma unroll
        for (int i = 0; i < 18; ++i) {
            if (t >= acc && t < acc + sizes[i]) { seg = i; off = t - acc; }
            acc += sizes[i];
        }
        if (fl == 1) a.dst[t] = bf2f(((const unsigned short*)a.src[seg])[off]);
        else         a.dst[t] = ((const float*)a.src[seg])[off];
    }
    if (t < N_PAIRS) atomicAdd(&cnt[pidx[t]], 1);
}

// block 0: CSR scan. blocks 1..25: T1/T2 tables + fp16 packing. grid 26 x 1024.
__global__ void k_scantab(const float* __restrict__ WF, float* __restrict__ T1,
                          float* __restrict__ T2, unsigned* __restrict__ PH,
                          const int* __restrict__ cnt, int* __restrict__ offs,
                          int* __restrict__ cur) {
    __shared__ int buf[1024];
    if (blockIdx.x == 0) {
        int tid = threadIdx.x;
        int base = tid * 10;
        int c[10]; int s = 0;
        #pragma unroll
        for (int i = 0; i < 10; ++i) {
            int idx = base + i;
            int v = (idx < N_ATOMS) ? cnt[idx] : 0;
            c[i] = v; s += v;
        }
        buf[tid] = s;
        __syncthreads();
        for (int off = 1; off < 1024; off <<= 1) {
            int v = (tid >= off) ? buf[tid - off] : 0;
            __syncthreads();
            buf[tid] += v;
            __syncthreads();
        }
        int run = buf[tid] - s;
        #pragma unroll
        for (int i = 0; i < 10; ++i) {
            int idx = base + i;
            if (idx < N_ATOMS) { offs[idx] = run; cur[idx] = run; run += c[i]; }
        }
        if (tid == 0) offs[N_ATOMS] = N_PAIRS;
        return;
    }
    int t = (blockIdx.x - 1) * 1024 + threadIdx.x;
    if (t < 6400) {
        int z = t >> 6, h = t & 63;
        const float* ez = WF + OFF_EMB + z * HH;
        const float* w2 = WF + OFF_W2 + h * 128;
        float s1 = 0.f, s2 = 0.f;
        #pragma unroll
        for (int k = 0; k < 64; ++k) {
            float e = ez[k];
            s1 += w2[k] * e;
            s2 += w2[64 + k] * e;
        }
        T1[z * HH + h] = s1;
        T2[z * HH + h] = s2;
    }
    if (t < PH_N) {
        int src;
        if (t < PH_L1) {
            int w = t >> 10, r = t & 1023;
            src = (w == 0 ? OFF_D1W : (w == 1 ? OFF_D2W : OFF_D3W)) + r * 2;
        } else if (t < PH_L2) {
            src = OFF_L1W + (t - PH_L1) * 2;
        } else if (t < PH_LT) {
            src = OFF_L2W + (t - PH_L2) * 2;
        } else {
            src = OFF_LT0 + (t - PH_LT) * 2;
        }
        PH[t] = packh2(WF[src], WF[src + 1]);
    }
}

// pair-parallel: gather/decode + unit vector + cutoff + full rbf precompute.
__global__ void k_fill(const int* __restrict__ pidx, const int* __restrict__ an,
                       const void* __restrict__ dij_v, const void* __restrict__ rij_v,
                       int* __restrict__ cur,
                       float4* __restrict__ dpack, int* __restrict__ znl,
                       unsigned* __restrict__ rbfp) {
    __shared__ int fdr[2];
    if (threadIdx.x < 64) {
        int fd = classify64((const unsigned short*)dij_v, threadIdx.x);
        int fr = classify64((const unsigned short*)rij_v, threadIdx.x);
        if (threadIdx.x == 0) { fdr[0] = fd; fdr[1] = fr; }
    }
    __syncthreads();
    int p = blockIdx.x * 256 + threadIdx.x;
    if (p >= N_PAIRS) return;
    int s = pidx[p];
    int dst = pidx[N_PAIRS + p];
    int pos = atomicAdd(&cur[s], 1);
    float d, rx, ry, rz;
    if (fdr[0] == 1) d = bf2f(((const unsigned short*)dij_v)[p]);
    else             d = ((const float*)dij_v)[p];
    if (fdr[1] == 1) {
        const unsigned short* r = (const unsigned short*)rij_v;
        rx = bf2f(r[3*p]); ry = bf2f(r[3*p+1]); rz = bf2f(r[3*p+2]);
    } else {
        const float* r = (const float*)rij_v;
        rx = r[3*p]; ry = r[3*p+1]; rz = r[3*p+2];
    }
    float inv = 1.0f / d;
    float rc = (d < 0.5f) ? 0.5f * (fcos2pi(d) + 1.0f) : 0.0f;
    dpack[pos] = make_float4(rx * inv, ry * inv, rz * inv, rc);
    znl[pos] = an[dst];
    float en = fexp2(NEG_ALPHA_L2 * d);
    unsigned* rp = rbfp + pos * 16;
    #pragma unroll
    for (int r2 = 0; r2 < 16; ++r2) {
        float t0 = en - (RBF_START + RBF_STEP * (float)(2 * r2));
        float t1 = en - (RBF_START + RBF_STEP * (float)(2 * r2 + 1));
        float v0 = fexp2(NEG_BETA_L2 * t0 * t0) * rc;
        float v1 = fexp2(NEG_BETA_L2 * t1 * t1) * rc;
        rp[r2] = packh2(v0, v1);
    }
}

// Pair accumulation: 4 waves/block, 1 atom/wave, ZERO LDS, weights in named regs.
__global__ __launch_bounds__(256, 2) void k_pair(
    const int* __restrict__ an,
    const float* __restrict__ WF,
    const int* __restrict__ offs,
    const float4* __restrict__ dpack, const int* __restrict__ znl,
    const unsigned* __restrict__ rbfp,
    const float* __restrict__ T1, const float* __restrict__ T2,
    const unsigned* __restrict__ PH,
    unsigned* __restrict__ accH)
{
    const int wave = threadIdx.x >> 6;
    const int h    = threadIdx.x & 63;
    const int n    = blockIdx.x * 4 + wave;

    // dp weight rows for this lane: 12 named uint4 (48 VGPRs, no arrays -> no scratch)
    const uint4* wp = (const uint4*)(PH + PH_DP);
    const uint4 w10 = wp[        h * 4 + 0], w11 = wp[        h * 4 + 1],
                w12 = wp[        h * 4 + 2], w13 = wp[        h * 4 + 3];
    const uint4 w20 = wp[256 +   h * 4 + 0], w21 = wp[256 +   h * 4 + 1],
                w22 = wp[256 +   h * 4 + 2], w23 = wp[256 +   h * 4 + 3];
    const uint4 w30 = wp[512 +   h * 4 + 0], w31 = wp[512 +   h * 4 + 1],
                w32 = wp[512 +   h * 4 + 2], w33 = wp[512 +   h * 4 + 3];

    const float ed1 = (WF + OFF_D1B)[h];
    const float ed2 = (WF + OFF_D2B)[h];
    const float ed3 = (WF + OFF_D3B)[h];
    const float zA  = (WF + OFF_B2)[h] + T1[an[n] * HH + h];

    float Is=0.f, sx=0.f, sy=0.f, sz=0.f;
    float Sxx=0.f, Syy=0.f, Szz=0.f, Sxy=0.f, Sxz=0.f, Syz=0.f;

    const int pbeg = offs[n], pend = offs[n + 1];
    const uint4* rbase = (const uint4*)rbfp;

    float4 dp_cur = make_float4(0.f, 0.f, 0.f, 0.f);
    uint4  r0c = {0,0,0,0}, r1c = {0,0,0,0}, r2c = {0,0,0,0}, r3c = {0,0,0,0};
    float  t2cur = 0.f;
    int    zn_n  = 0;
    if (pbeg < pend) {
        dp_cur = dpack[pbeg];
        r0c = rbase[pbeg*4+0]; r1c = rbase[pbeg*4+1];
        r2c = rbase[pbeg*4+2]; r3c = rbase[pbeg*4+3];
        t2cur = T2[znl[pbeg] * HH + h];
        if (pbeg + 1 < pend) zn_n = znl[pbeg + 1];
    }

    for (int ii = pbeg; ii < pend; ++ii) {
        const float4 dpv = dp_cur;
        const uint4  b0 = r0c, b1 = r1c, b2 = r2c, b3 = r3c;
        const float  t2v = t2cur;
        if (ii + 1 < pend) {
            dp_cur = dpack[ii + 1];
            r0c = rbase[(ii+1)*4+0]; r1c = rbase[(ii+1)*4+1];
            r2c = rbase[(ii+1)*4+2]; r3c = rbase[(ii+1)*4+3];
            t2cur = T2[zn_n * HH + h];
            if (ii + 2 < pend) zn_n = znl[ii + 2];
        }

        float g1 = ed1, g2 = ed2, g3 = ed3;
        g1 = dot16v(w10, b0, g1); g1 = dot16v(w11, b1, g1);
        g1 = dot16v(w12, b2, g1); g1 = dot16v(w13, b3, g1);
        g2 = dot16v(w20, b0, g2); g2 = dot16v(w21, b1, g2);
        g2 = dot16v(w22, b2, g2); g2 = dot16v(w23, b3, g2);
        g3 = dot16v(w30, b0, g3); g3 = dot16v(w31, b1, g3);
        g3 = dot16v(w32, b2, g3); g3 = dot16v(w33, b3, g3);

        float ux = dpv.x, uy = dpv.y, uz = dpv.z, rc = dpv.w;
        float Cc = rc * (zA + t2v);
        float f1 = g1 * Cc;
        float f2 = g2 * Cc * 10.0f;
        float f3 = g3 * Cc * 100.0f;

        Is += f1;
        sx += f2 * ux;  sy += f2 * uy;  sz += f2 * uz;
        float q = (ux*ux + uy*uy + uz*uz) * (1.0f / 3.0f);
        Sxx += f3 * (ux*ux - q);
        Syy += f3 * (uy*uy - q);
        Szz += f3 * (uz*uz - q);
        Sxy += f3 * (ux*uy);
        Sxz += f3 * (ux*uz);
        Syz += f3 * (uy*uz);
    }

    // tn + LayerNorm (f32)
    float tn = 3.0f*Is*Is + 2.0f*(sx*sx + sy*sy + sz*sz)
             + Sxx*Sxx + Syy*Syy + Szz*Szz
             + 2.0f*(Sxy*Sxy + Sxz*Sxz + Syz*Syz);
    float s1 = tn, s2 = tn * tn;
    #pragma unroll
    for (int o = 32; o > 0; o >>= 1) {
        s1 += __shfl_xor(s1, o);
        s2 += __shfl_xor(s2, o);
    }
    float mu  = s1 * (1.0f / 64.0f);
    float var = s2 * (1.0f / 64.0f) - mu * mu;
    float nv  = (tn - mu) * rsqrtf(var + 1e-5f) * (WF + OFF_LNG)[h] + (WF + OFF_LNB)[h];

    float vals[11] = {Is, sx, sy, sz, Sxx, Syy, Szz, Sxy, Sxz, Syz, nv};
    #pragma unroll
    for (int c = 0; c < 11; ++c) {
        float pv = __shfl_xor(vals[c], 1);
        if ((h & 1) == 0)
            accH[((n * 11 + c) << 5) + (h >> 1)] = packh2(vals[c], pv);
    }
}

// Epilogue: MLP + transform. ls2 fp16 in LDS; ls1/lt from global (L1-resident).
__global__ __launch_bounds__(256, 2) void k_post(
    const float* __restrict__ WF,
    const unsigned* __restrict__ PH,
    const unsigned* __restrict__ accH,
    float* __restrict__ out)
{
    __shared__ __align__(16) unsigned wL2[192 * 68];
    __shared__ __align__(16) unsigned acch[4][12 * 32];
    __shared__ __align__(16) unsigned y1h[4][64];
    __shared__ __align__(16) unsigned y2h[4][96];

    for (int q = threadIdx.x; q < 12288; q += 256) {
        int m = q >> 6, u = q & 63;
        wL2[m * 68 + u] = PH[PH_L2 + q];
    }
    __syncthreads();

    const int wave = threadIdx.x >> 6;
    const int h    = threadIdx.x & 63;
    const int gw   = blockIdx.x * 4 + wave;
    const int GW   = gridDim.x * 4;

    const uint4* l1base = (const uint4*)(PH + PH_L1);
    const uint4* lt0 = (const uint4*)(PH + PH_LT) + h * 8;
    const uint4* lt1 = (const uint4*)(PH + PH_LT + 2048) + h * 8;
    const uint4* lt2 = (const uint4*)(PH + PH_LT + 4096) + h * 8;

    for (int n = gw; n < N_ATOMS; n += GW) {
        if (h < 32) {
            #pragma unroll
            for (int c = 0; c < 11; ++c)
                acch[wave][c * 32 + h] = accH[((n * 11 + c) << 5) + h];
        }
        __builtin_amdgcn_wave_barrier();

        const uint4* nvh = (const uint4*)&acch[wave][10 * 32];

        float ya = (WF + OFF_L1B)[h];
        float yb = (WF + OFF_L1B)[h + 64];
        {
            const uint4* ra = l1base + h * 8;
            const uint4* rb = l1base + (h + 64) * 8;
            #pragma unroll
            for (int k = 0; k < 8; ++k) {
                ya = dot16h(ra + k, nvh + k, ya);
                yb = dot16h(rb + k, nvh + k, yb);
            }
        }
        ya = fsilu(ya); yb = fsilu(yb);
        {
            float pa = __shfl_xor(ya, 1);
            float pb = __shfl_xor(yb, 1);
            if ((h & 1) == 0) {
                y1h[wave][(h >> 1)]      = packh2(ya, pa);
                y1h[wave][32 + (h >> 1)] = packh2(yb, pb);
            }
        }
        __builtin_amdgcn_wave_barrier();

        const uint4* y1p = (const uint4*)&y1h[wave][0];
        float z0 = (WF + OFF_L2B)[h];
        float z1 = (WF + OFF_L2B)[h + 64];
        float z2 = (WF + OFF_L2B)[h + 128];
        {
            const uint4* r0 = (const uint4*)&wL2[(h)       * 68];
            const uint4* r1 = (const uint4*)&wL2[(h + 64)  * 68];
            const uint4* r2 = (const uint4*)&wL2[(h + 128) * 68];
            #pragma unroll
            for (int k = 0; k < 16; ++k) {
                uint4 x = y1p[k];
                z0 = dot16v(r0[k], x, z0);
                z1 = dot16v(r1[k], x, z1);
                z2 = dot16v(r2[k], x, z2);
            }
        }
        z0 = fsilu(z0); z1 = fsilu(z1); z2 = fsilu(z2);
        {
            float p0 = __shfl_xor(z0, 1);
            float p1 = __shfl_xor(z1, 1);
            float p2 = __shfl_xor(z2, 1);
            if ((h & 1) == 0) {
                y2h[wave][(h >> 1)]      = packh2(z0, p0);
                y2h[wave][32 + (h >> 1)] = packh2(z1, p1);
                y2h[wave][64 + (h >> 1)] = packh2(z2, p2);
            }
        }
        __builtin_amdgcn_wave_barrier();

        float n0, n1, n2;
        {
            int i0 = 3 * h;
            unsigned u0 = y2h[wave][i0 >> 1];
            unsigned u1 = y2h[wave][(i0 >> 1) + 1];
            h2_t a = u2h(u0), b = u2h(u1);
            if (i0 & 1) { n0 = (float)a.y; n1 = (float)b.x; n2 = (float)b.y; }
            else        { n0 = (float)a.x; n1 = (float)a.y; n2 = (float)b.x; }
        }

        const uint4* aI  = (const uint4*)&acch[wave][0];
        const uint4* aAx = (const uint4*)&acch[wave][32];
        const uint4* aAy = (const uint4*)&acch[wave][64];
        const uint4* aAz = (const uint4*)&acch[wave][96];
        const uint4* aXX = (const uint4*)&acch[wave][128];
        const uint4* aYY = (const uint4*)&acch[wave][160];
        const uint4* aZZ = (const uint4*)&acch[wave][192];
        const uint4* aXY = (const uint4*)&acch[wave][224];
        const uint4* aXZ = (const uint4*)&acch[wave][256];
        const uint4* aYZ = (const uint4*)&acch[wave][288];

        float P0=0.f, PAx=0.f, PAy=0.f, PAz=0.f;
        float Q0=0.f, Q1=0.f, Q2=0.f, Q3=0.f, Q4=0.f, Q5=0.f;
        #pragma unroll
        for (int k = 0; k < 8; ++k) {
            P0  = dot16h(lt0 + k, aI  + k, P0);
            PAx = dot16h(lt1 + k, aAx + k, PAx);
            PAy = dot16h(lt1 + k, aAy + k, PAy);
            PAz = dot16h(lt1 + k, aAz + k, PAz);
            Q0  = dot16h(lt2 + k, aXX + k, Q0);
            Q1  = dot16h(lt2 + k, aYY + k, Q1);
            Q2  = dot16h(lt2 + k, aZZ + k, Q2);
            Q3  = dot16h(lt2 + k, aXY + k, Q3);
            Q4  = dot16h(lt2 + k, aXZ + k, Q4);
            Q5  = dot16h(lt2 + k, aYZ + k, Q5);
        }
        float Iv = P0 * n0;
        float Ax = PAx * n1, Ay = PAy * n1, Az = PAz * n1;
        float Xx = Q0 * n2, Yy = Q1 * n2, Zz = Q2 * n2;
        float Xy = Q3 * n2, Xz = Q4 * n2, Yz = Q5 * n2;

        float* o = out + (size_t)n * 576 + h * 9;
        o[0] =  Iv + Xx;  o[1] = -Az + Xy;  o[2] =  Ay + Xz;
        o[3] =  Az + Xy;  o[4] =  Iv + Yy;  o[5] = -Ax + Yz;
        o[6] = -Ay + Xz;  o[7] =  Ax + Yz;  o[8] =  Iv + Zz;
        __builtin_amdgcn_wave_barrier();
    }
}

extern "C" void kernel_launch(void* const* d_in, const int* in_sizes, int n_in,
                              void* d_out, int out_size, void* d_ws, size_t ws_size,
                              hipStream_t stream) {
    const int* an   = (const int*)d_in[0];
    const int* pidx = (const int*)d_in[1];

    char* ws = (char*)d_ws;
    float*    WF    = (float*)(ws + WS_WF);
    int*      cnt   = (int*)(ws + WS_CNT);
    int*      offs  = (int*)(ws + WS_OFF);
    int*      cur   = (int*)(ws + WS_CUR);
    float*    T1    = (float*)(ws + WS_T1);
    float*    T2    = (float*)(ws + WS_T2);
    unsigned* PH    = (unsigned*)(ws + WS_PH);
    float4*   dpack = (float4*)(ws + WS_DPK);
    int*      znl   = (int*)(ws + WS_ZNL);
    unsigned* rbfp  = (unsigned*)(ws + WS_RBF);
    unsigned* accH  = (unsigned*)(ws + WS_ACCH);
    float*    out   = (float*)d_out;

    hipMemsetAsync(cnt, 0, N_ATOMS * sizeof(int), stream);

    ConvArgs ca;
    for (int i = 0; i < 18; ++i) ca.src[i] = d_in[4 + i];
    ca.dst = WF;
    k_prep<<<(N_PAIRS + 255) / 256, 256, 0, stream>>>(ca, pidx, cnt);
    k_scantab<<<26, 1024, 0, stream>>>(WF, T1, T2, PH, cnt, offs, cur);
    k_fill<<<(N_PAIRS + 255) / 256, 256, 0, stream>>>(pidx, an, d_in[2], d_in[3],
                                                      cur, dpack, znl, rbfp);
    k_pair<<<2500, 256, 0, stream>>>(an, WF, offs, dpack, znl, rbfp, T1, T2, PH, accH);
    k_post<<<512, 256, 0, stream>>>(WF, PH, accH, out);
}